// Round 1
// baseline (450.857 us; speedup 1.0000x reference)
//
#include <hip/hip_runtime.h>
#include <math.h>

// ---------------------------------------------------------------------------
// MyNet: two 1024x1024x3 images -> 3x3 matrix.
// Pipeline: fused enc+embed conv3x3(3->32)+maxpool2 -> c1,c2 (32,512,512)
//           maxpool2 -> p1,p2 (32,256,256)
//           pixel_match@512 + maxpool2 -> feat ch0..19
//           pixel_match@256            -> feat ch20..39
//           conv5x5(p1-p2,32->8)+leaky -> feat ch40..47
//           1x1 conv 48->64 -> f1out; adaptive_max_pool3 -> (64,3,3)
//           conv3x3(64->128) -> L2-normalize -> matmul(6x128) -> assemble 3x3
// ---------------------------------------------------------------------------

__global__ void fuse_weights_kernel(const float* __restrict__ enc_w,
                                    const float* __restrict__ enc_b,
                                    const float* __restrict__ embed_w,
                                    const float* __restrict__ embed_b,
                                    float* __restrict__ weff,
                                    float* __restrict__ beff) {
    int t = threadIdx.x;
    for (int idx = t; idx < 32 * 27; idx += blockDim.x) {
        int o = idx / 27, r = idx % 27;
        float s = 0.f;
        for (int k = 0; k < 24; ++k) s += embed_w[o * 24 + k] * enc_w[k * 27 + r];
        weff[idx] = s;
    }
    if (t < 32) {
        float s = embed_b[t];
        for (int k = 0; k < 24; ++k) s += embed_w[t * 24 + k] * enc_b[k];
        beff[t] = s;
    }
}

// One thread per output pixel of c (512x512); computes effective 3x3 conv
// (3->32) at the 4 source pixels (1024 res) and maxpools them.
__global__ __launch_bounds__(256) void coding_kernel(
    const float* __restrict__ x1, const float* __restrict__ x2,
    const float* __restrict__ weff, const float* __restrict__ beff,
    float* __restrict__ c1, float* __restrict__ c2) {
    __shared__ float sw[864];
    __shared__ float sb[32];
    int tid = threadIdx.y * 16 + threadIdx.x;
    for (int i = tid; i < 864; i += 256) sw[i] = weff[i];
    if (tid < 32) sb[tid] = beff[tid];
    __syncthreads();
    const float* x = (blockIdx.z == 0) ? x1 : x2;
    float* c = (blockIdx.z == 0) ? c1 : c2;
    int w = blockIdx.x * 16 + threadIdx.x;
    int h = blockIdx.y * 16 + threadIdx.y;
    float m[32];
#pragma unroll
    for (int o = 0; o < 32; ++o) m[o] = -INFINITY;
    for (int dy = 0; dy < 2; ++dy)
        for (int dx = 0; dx < 2; ++dx) {
            int Y = 2 * h + dy, X = 2 * w + dx;
            float acc[32];
#pragma unroll
            for (int o = 0; o < 32; ++o) acc[o] = sb[o];
            for (int ci = 0; ci < 3; ++ci)
                for (int ky = 0; ky < 3; ++ky) {
                    int yy = Y + ky - 1;
                    if (yy < 0 || yy >= 1024) continue;
                    for (int kx = 0; kx < 3; ++kx) {
                        int xx = X + kx - 1;
                        if (xx < 0 || xx >= 1024) continue;
                        float xv = x[ci * 1048576 + yy * 1024 + xx];
                        const float* wp = &sw[ci * 9 + ky * 3 + kx];
#pragma unroll
                        for (int o = 0; o < 32; ++o)
                            acc[o] = fmaf(wp[o * 27], xv, acc[o]);
                    }
                }
#pragma unroll
            for (int o = 0; o < 32; ++o) m[o] = fmaxf(m[o], acc[o]);
        }
    int pix = h * 512 + w;
#pragma unroll
    for (int o = 0; o < 32; ++o) c[o * 262144 + pix] = m[o];
}

// maxpool2 (512->256) for both images, all 32 channels.
__global__ void maxpool_kernel(const float* __restrict__ c1,
                               const float* __restrict__ c2,
                               float* __restrict__ p1, float* __restrict__ p2) {
    int idx = blockIdx.x * 256 + threadIdx.x;
    if (idx >= 2 * 32 * 65536) return;
    int img = idx >> 21;
    int r = idx & 2097151;
    int c = r >> 16;
    int pix = r & 65535;
    int h = pix >> 8, w = pix & 255;
    const float* src = (img ? c2 : c1) + c * 262144;
    float* dst = (img ? p2 : p1);
    int base = (2 * h) * 512 + 2 * w;
    float v = fmaxf(fmaxf(src[base], src[base + 1]),
                    fmaxf(src[base + 512], src[base + 513]));
    dst[c * 65536 + pix] = v;
}

// pixel_match at 512 res fused with maxpool2 -> feat channels 0..19.
__global__ __launch_bounds__(256) void pm512_pool_kernel(
    const float* __restrict__ c1, const float* __restrict__ c2,
    float* __restrict__ feat) {
    int w = blockIdx.x * 16 + threadIdx.x;
    int h = blockIdx.y * 16 + threadIdx.y;
    float mx[20];
#pragma unroll
    for (int k = 0; k < 20; ++k) mx[k] = -INFINITY;
    for (int dy = 0; dy < 2; ++dy)
        for (int dx = 0; dx < 2; ++dx) {
            int sh = 2 * h + dy, sw = 2 * w + dx;
            float d1[9], d2[9];
            bool interior = (sh >= 1 && sh <= 510 && sw >= 1 && sw <= 510);
            if (interior) {
                float a1[9], a2[9];
#pragma unroll
                for (int k = 0; k < 9; ++k) { a1[k] = 0.f; a2[k] = 0.f; }
                int ctr = sh * 512 + sw;
                for (int c = 0; c < 32; ++c) {
                    const float* b1 = c1 + c * 262144;
                    const float* b2 = c2 + c * 262144;
                    float y1 = b1[ctr], y2 = b2[ctr];
#pragma unroll
                    for (int dh = 0; dh < 3; ++dh)
#pragma unroll
                        for (int dw = 0; dw < 3; ++dw) {
                            int off = (sh + dh - 1) * 512 + (sw + dw - 1);
                            float n1 = b1[off], n2 = b2[off];
                            float t1 = n1 - y2, t2 = n2 - y1;
                            a1[dh * 3 + dw] = fmaf(t1, t1, a1[dh * 3 + dw]);
                            a2[dh * 3 + dw] = fmaf(t2, t2, a2[dh * 3 + dw]);
                        }
                }
                float s1 = 0.f, s2 = 0.f;
#pragma unroll
                for (int k = 0; k < 9; ++k) {
                    d1[k] = 1.0f / sqrtf(a1[k] + 0.01f);
                    d2[k] = 1.0f / sqrtf(a2[k] + 0.01f);
                    s1 += d1[k];
                    s2 += d2[k];
                }
                float i1 = 1.0f / s1, i2 = 1.0f / s2;
#pragma unroll
                for (int k = 0; k < 9; ++k) { d1[k] *= i1; d2[k] *= i2; }
            } else {
#pragma unroll
                for (int k = 0; k < 9; ++k) {
                    d1[k] = 1.0f / 9.0f;
                    d2[k] = 1.0f / 9.0f;
                }
            }
#pragma unroll
            for (int k = 0; k < 9; ++k) {
                mx[k] = fmaxf(mx[k], d1[k]);
                mx[9 + k] = fmaxf(mx[9 + k], d2[k]);
            }
            float ph = 2.0f * sh / 511.0f - 1.0f;
            float pw = 2.0f * sw / 511.0f - 1.0f;
            mx[18] = fmaxf(mx[18], ph);
            mx[19] = fmaxf(mx[19], pw);
        }
    int pix = h * 256 + w;
#pragma unroll
    for (int k = 0; k < 20; ++k) feat[k * 65536 + pix] = mx[k];
}

// pixel_match at 256 res -> feat channels 20..39.
__global__ __launch_bounds__(256) void pm256_kernel(
    const float* __restrict__ p1, const float* __restrict__ p2,
    float* __restrict__ feat) {
    int w = blockIdx.x * 16 + threadIdx.x;
    int h = blockIdx.y * 16 + threadIdx.y;
    float d1[9], d2[9];
    bool interior = (h >= 1 && h <= 254 && w >= 1 && w <= 254);
    if (interior) {
        float a1[9], a2[9];
#pragma unroll
        for (int k = 0; k < 9; ++k) { a1[k] = 0.f; a2[k] = 0.f; }
        int ctr = h * 256 + w;
        for (int c = 0; c < 32; ++c) {
            const float* b1 = p1 + c * 65536;
            const float* b2 = p2 + c * 65536;
            float y1 = b1[ctr], y2 = b2[ctr];
#pragma unroll
            for (int dh = 0; dh < 3; ++dh)
#pragma unroll
                for (int dw = 0; dw < 3; ++dw) {
                    int off = (h + dh - 1) * 256 + (w + dw - 1);
                    float n1 = b1[off], n2 = b2[off];
                    float t1 = n1 - y2, t2 = n2 - y1;
                    a1[dh * 3 + dw] = fmaf(t1, t1, a1[dh * 3 + dw]);
                    a2[dh * 3 + dw] = fmaf(t2, t2, a2[dh * 3 + dw]);
                }
        }
        float s1 = 0.f, s2 = 0.f;
#pragma unroll
        for (int k = 0; k < 9; ++k) {
            d1[k] = 1.0f / sqrtf(a1[k] + 0.01f);
            d2[k] = 1.0f / sqrtf(a2[k] + 0.01f);
            s1 += d1[k];
            s2 += d2[k];
        }
        float i1 = 1.0f / s1, i2 = 1.0f / s2;
#pragma unroll
        for (int k = 0; k < 9; ++k) { d1[k] *= i1; d2[k] *= i2; }
    } else {
#pragma unroll
        for (int k = 0; k < 9; ++k) {
            d1[k] = 1.0f / 9.0f;
            d2[k] = 1.0f / 9.0f;
        }
    }
    int pix = h * 256 + w;
#pragma unroll
    for (int k = 0; k < 9; ++k) {
        feat[(20 + k) * 65536 + pix] = d1[k];
        feat[(29 + k) * 65536 + pix] = d2[k];
    }
    feat[38 * 65536 + pix] = 2.0f * h / 255.0f - 1.0f;
    feat[39 * 65536 + pix] = 2.0f * w / 255.0f - 1.0f;
}

// conv5x5 (32->8, pad 2) on (p1-p2) + leaky_relu -> feat channels 40..47.
__global__ __launch_bounds__(256) void dense_kernel(
    const float* __restrict__ p1, const float* __restrict__ p2,
    const float* __restrict__ dw, const float* __restrict__ db,
    float* __restrict__ feat) {
    __shared__ float sw[6400];
    __shared__ float sb[8];
    int tid = threadIdx.x;
    for (int i = tid; i < 6400; i += 256) sw[i] = dw[i];
    if (tid < 8) sb[tid] = db[tid];
    __syncthreads();
    int pix = blockIdx.x * 256 + tid;
    int h = pix >> 8, w = pix & 255;
    float acc[8];
#pragma unroll
    for (int o = 0; o < 8; ++o) acc[o] = sb[o];
    for (int ci = 0; ci < 32; ++ci) {
        const float* b1 = p1 + ci * 65536;
        const float* b2 = p2 + ci * 65536;
        for (int ky = 0; ky < 5; ++ky) {
            int yy = h + ky - 2;
            if (yy < 0 || yy >= 256) continue;
            for (int kx = 0; kx < 5; ++kx) {
                int xx = w + kx - 2;
                if (xx < 0 || xx >= 256) continue;
                float v = b1[yy * 256 + xx] - b2[yy * 256 + xx];
#pragma unroll
                for (int o = 0; o < 8; ++o)
                    acc[o] = fmaf(sw[((o * 32 + ci) * 5 + ky) * 5 + kx], v, acc[o]);
            }
        }
    }
#pragma unroll
    for (int o = 0; o < 8; ++o) {
        float v = acc[o];
        v = (v >= 0.f) ? v : 0.01f * v;
        feat[(40 + o) * 65536 + pix] = v;
    }
}

// 1x1 conv 48->64 over feat.
__global__ __launch_bounds__(256) void f1_kernel(
    const float* __restrict__ feat, const float* __restrict__ f1w,
    const float* __restrict__ f1b, float* __restrict__ out) {
    __shared__ float sw[3072];
    __shared__ float sb[64];
    int tid = threadIdx.x;
    for (int i = tid; i < 3072; i += 256) sw[i] = f1w[i];
    if (tid < 64) sb[tid] = f1b[tid];
    __syncthreads();
    int pix = blockIdx.x * 256 + tid;
    float f[48];
#pragma unroll
    for (int c = 0; c < 48; ++c) f[c] = feat[c * 65536 + pix];
    for (int o = 0; o < 64; ++o) {
        float a = sb[o];
#pragma unroll
        for (int c = 0; c < 48; ++c) a = fmaf(sw[o * 48 + c], f[c], a);
        out[o * 65536 + pix] = a;
    }
}

// adaptive_max_pool3: one block per (channel, i, j); overlapping regions.
__global__ __launch_bounds__(256) void pool3_kernel(
    const float* __restrict__ f1out, float* __restrict__ pooled) {
    int b = blockIdx.x;  // 64*9
    int c = b / 9, ij = b % 9, i = ij / 3, j = ij % 3;
    int hs = (i * 256) / 3, he = ((i + 1) * 256 + 2) / 3;
    int ws = (j * 256) / 3, we = ((j + 1) * 256 + 2) / 3;
    const float* src = f1out + c * 65536;
    int nh = he - hs, nw = we - ws, tot = nh * nw;
    float m = -INFINITY;
    for (int t = threadIdx.x; t < tot; t += 256) {
        int r = t / nw, q = t - r * nw;
        m = fmaxf(m, src[(hs + r) * 256 + (ws + q)]);
    }
    for (int off = 32; off > 0; off >>= 1) m = fmaxf(m, __shfl_down(m, off, 64));
    __shared__ float red[4];
    if ((threadIdx.x & 63) == 0) red[threadIdx.x >> 6] = m;
    __syncthreads();
    if (threadIdx.x == 0)
        pooled[b] = fmaxf(fmaxf(red[0], red[1]), fmaxf(red[2], red[3]));
}

// f2 conv (64,3,3)->128, L2-normalize, f3 matmul -> 6, assemble 3x3 output.
__global__ __launch_bounds__(128) void final_kernel(
    const float* __restrict__ pooled, const float* __restrict__ f2w,
    const float* __restrict__ f2b, const float* __restrict__ f3w,
    const float* __restrict__ f3b, float* __restrict__ out) {
    __shared__ float xn[128];
    __shared__ float red[2];
    __shared__ float ov[6];
    int t = threadIdx.x;
    float a = f2b[t];
    for (int c = 0; c < 64; ++c)
#pragma unroll
        for (int k = 0; k < 9; ++k)
            a = fmaf(f2w[t * 576 + c * 9 + k], pooled[c * 9 + k], a);
    float sq = a * a;
    for (int off = 32; off > 0; off >>= 1) sq += __shfl_down(sq, off, 64);
    if ((t & 63) == 0) red[t >> 6] = sq;
    __syncthreads();
    float tmp = red[0] + red[1] + 0.001f;
    float scale = 1.0f / sqrtf(tmp);
    xn[t] = a * scale;
    __syncthreads();
    if (t < 6) {
        float o = f3b[t];
        for (int k = 0; k < 128; ++k) o = fmaf(f3w[t * 128 + k], xn[k], o);
        ov[t] = o;
    }
    __syncthreads();
    if (t < 9) {
        int r = t / 3, cc = t % 3;
        float v = 0.f;
        if (r < 2) {
            float x = ov[r * 3 + cc];
            float cl = fminf(fmaxf(x, -0.11f), 0.11f);
            v = cl + 0.01f * x;
        }
        if (r == cc) v += 1.0f;
        out[t] = v;
    }
}

extern "C" void kernel_launch(void* const* d_in, const int* in_sizes, int n_in,
                              void* d_out, int out_size, void* d_ws,
                              size_t ws_size, hipStream_t stream) {
    const float* x1 = (const float*)d_in[0];
    const float* x2 = (const float*)d_in[1];
    const float* enc_w = (const float*)d_in[2];
    const float* enc_b = (const float*)d_in[3];
    const float* embed_w = (const float*)d_in[4];
    const float* embed_b = (const float*)d_in[5];
    const float* dense_w = (const float*)d_in[6];
    const float* dense_b = (const float*)d_in[7];
    const float* f1_w = (const float*)d_in[8];
    const float* f1_b = (const float*)d_in[9];
    const float* f2_w = (const float*)d_in[10];
    const float* f2_b = (const float*)d_in[11];
    const float* f3_w = (const float*)d_in[12];
    const float* f3_b = (const float*)d_in[13];

    float* ws = (float*)d_ws;
    float* weff = ws;                   // 864
    float* beff = ws + 864;             // 32
    float* c1 = ws + 1024;              // 32*512*512 = 8388608
    float* c2 = c1 + 8388608;
    float* p1 = c2 + 8388608;           // 32*256*256 = 2097152
    float* p2 = p1 + 2097152;
    float* feat = p2 + 2097152;         // 48*256*256 = 3145728
    float* pooled = feat + 3145728;     // 576
    float* f1o = c1;                    // alias: c1 dead after pm512/maxpool

    fuse_weights_kernel<<<1, 256, 0, stream>>>(enc_w, enc_b, embed_w, embed_b,
                                               weff, beff);
    coding_kernel<<<dim3(32, 32, 2), dim3(16, 16), 0, stream>>>(
        x1, x2, weff, beff, c1, c2);
    maxpool_kernel<<<(2 * 32 * 65536 + 255) / 256, 256, 0, stream>>>(c1, c2, p1,
                                                                     p2);
    pm512_pool_kernel<<<dim3(16, 16), dim3(16, 16), 0, stream>>>(c1, c2, feat);
    pm256_kernel<<<dim3(16, 16), dim3(16, 16), 0, stream>>>(p1, p2, feat);
    dense_kernel<<<256, 256, 0, stream>>>(p1, p2, dense_w, dense_b, feat);
    f1_kernel<<<256, 256, 0, stream>>>(feat, f1_w, f1_b, f1o);
    pool3_kernel<<<576, 256, 0, stream>>>(f1o, pooled);
    final_kernel<<<1, 128, 0, stream>>>(pooled, f2_w, f2_b, f3_w, f3_b,
                                        (float*)d_out);
}

// Round 2
// 433.994 us; speedup vs baseline: 1.0389x; 1.0389x over previous
//
#include <hip/hip_runtime.h>
#include <math.h>

// ---------------------------------------------------------------------------
// MyNet: two 1024x1024x3 images -> 3x3 matrix.
// R2: parallelism fixes. Every 256-block kernel (1 block/CU, 10% occupancy)
// redecomposed to >=1024 blocks. Coding kernel: transposed weights + b128
// broadcasts + register input patch (was ~3456 ds_read/wave, LDS-bound).
// ---------------------------------------------------------------------------

__global__ void fuse_weights_kernel(const float* __restrict__ enc_w,
                                    const float* __restrict__ enc_b,
                                    const float* __restrict__ embed_w,
                                    const float* __restrict__ embed_b,
                                    float* __restrict__ weff_t,
                                    float* __restrict__ beff) {
    int t = threadIdx.x;
    // weff_t[r*32+o] = sum_k embed_w[o,k] * enc_w[k,r]   (r = tap 0..26)
    for (int idx = t; idx < 27 * 32; idx += blockDim.x) {
        int r = idx >> 5, o = idx & 31;
        float s = 0.f;
        for (int k = 0; k < 24; ++k) s += embed_w[o * 24 + k] * enc_w[k * 27 + r];
        weff_t[idx] = s;
    }
    if (t < 32) {
        float s = embed_b[t];
        for (int k = 0; k < 24; ++k) s += embed_w[t * 24 + k] * enc_b[k];
        beff[t] = s;
    }
}

// Fused enc+embed 3x3 conv (3->32) + maxpool2. One thread per c-pixel (512^2).
// Input 4x4 patch in registers; weights streamed as float4 LDS broadcasts.
__global__ __launch_bounds__(256) void coding_kernel(
    const float* __restrict__ x1, const float* __restrict__ x2,
    const float* __restrict__ weff_t, const float* __restrict__ beff,
    float* __restrict__ c1, float* __restrict__ c2) {
    __shared__ float swT[864];  // [27][32]
    __shared__ float sb[32];
    int tx = threadIdx.x, ty = threadIdx.y;
    int tid = ty * 16 + tx;
    for (int i = tid; i < 864; i += 256) swT[i] = weff_t[i];
    if (tid < 32) sb[tid] = beff[tid];
    __syncthreads();
    const float* x = blockIdx.z ? x2 : x1;
    float* c = blockIdx.z ? c2 : c1;
    int h = blockIdx.y * 16 + ty, w = blockIdx.x * 16 + tx;
    int Y = 2 * h, X = 2 * w;
    float in[3][4][4];
    bool interior_blk = (blockIdx.x > 0 && blockIdx.x < 31 &&
                         blockIdx.y > 0 && blockIdx.y < 31);
    if (interior_blk) {
#pragma unroll
        for (int ci = 0; ci < 3; ++ci)
#pragma unroll
            for (int yy = 0; yy < 4; ++yy) {
                const float* row = x + ci * 1048576 + (Y - 1 + yy) * 1024 + X - 1;
#pragma unroll
                for (int xx = 0; xx < 4; ++xx) in[ci][yy][xx] = row[xx];
            }
    } else {
#pragma unroll
        for (int ci = 0; ci < 3; ++ci)
#pragma unroll
            for (int yy = 0; yy < 4; ++yy)
#pragma unroll
                for (int xx = 0; xx < 4; ++xx) {
                    int gy = Y - 1 + yy, gx = X - 1 + xx;
                    in[ci][yy][xx] =
                        (gy >= 0 && gy < 1024 && gx >= 0 && gx < 1024)
                            ? x[ci * 1048576 + gy * 1024 + gx]
                            : 0.f;
                }
    }
    int pix = h * 512 + w;
#pragma unroll
    for (int og = 0; og < 2; ++og) {
        float acc[4][16];
#pragma unroll
        for (int p = 0; p < 4; ++p)
#pragma unroll
            for (int oo = 0; oo < 16; ++oo) acc[p][oo] = sb[og * 16 + oo];
#pragma unroll
        for (int ci = 0; ci < 3; ++ci)
#pragma unroll
            for (int ky = 0; ky < 3; ++ky)
#pragma unroll
                for (int kx = 0; kx < 3; ++kx) {
                    const float4* wp =
                        (const float4*)&swT[(ci * 9 + ky * 3 + kx) * 32 + og * 16];
                    float4 w0 = wp[0], w1 = wp[1], w2 = wp[2], w3 = wp[3];
                    float wv[16] = {w0.x, w0.y, w0.z, w0.w, w1.x, w1.y, w1.z, w1.w,
                                    w2.x, w2.y, w2.z, w2.w, w3.x, w3.y, w3.z, w3.w};
#pragma unroll
                    for (int p = 0; p < 4; ++p) {
                        float xv = in[ci][(p >> 1) + ky][(p & 1) + kx];
#pragma unroll
                        for (int oo = 0; oo < 16; ++oo)
                            acc[p][oo] = fmaf(wv[oo], xv, acc[p][oo]);
                    }
                }
#pragma unroll
        for (int oo = 0; oo < 16; ++oo) {
            float m = fmaxf(fmaxf(acc[0][oo], acc[1][oo]),
                            fmaxf(acc[2][oo], acc[3][oo]));
            c[(og * 16 + oo) * 262144 + pix] = m;
        }
    }
}

// maxpool2 (512->256) for both images, all 32 channels.
__global__ void maxpool_kernel(const float* __restrict__ c1,
                               const float* __restrict__ c2,
                               float* __restrict__ p1, float* __restrict__ p2) {
    int idx = blockIdx.x * 256 + threadIdx.x;
    if (idx >= 2 * 32 * 65536) return;
    int img = idx >> 21;
    int r = idx & 2097151;
    int c = r >> 16;
    int pix = r & 65535;
    int h = pix >> 8, w = pix & 255;
    const float* src = (img ? c2 : c1) + c * 262144;
    float* dst = (img ? p2 : p1);
    int base = (2 * h) * 512 + 2 * w;
    float v = fmaxf(fmaxf(src[base], src[base + 1]),
                    fmaxf(src[base + 512], src[base + 513]));
    dst[c * 65536 + pix] = v;
}

// pixel_match at 512 res + fused maxpool2 via in-wave 2x2 shfl reduce.
// One thread per SOURCE pixel (512^2 threads, 1024 blocks).
__global__ __launch_bounds__(256) void pm512_pool_kernel(
    const float* __restrict__ c1, const float* __restrict__ c2,
    float* __restrict__ feat) {
    int tx = threadIdx.x, ty = threadIdx.y;
    int sw = blockIdx.x * 16 + tx;
    int sh = blockIdx.y * 16 + ty;
    float d[20];
    bool interior = (sh >= 1 && sh <= 510 && sw >= 1 && sw <= 510);
    if (interior) {
        float a1[9], a2[9];
#pragma unroll
        for (int k = 0; k < 9; ++k) { a1[k] = 0.f; a2[k] = 0.f; }
        int ctr = sh * 512 + sw;
        for (int c = 0; c < 32; ++c) {
            const float* b1 = c1 + c * 262144;
            const float* b2 = c2 + c * 262144;
            float y1 = b1[ctr], y2 = b2[ctr];
#pragma unroll
            for (int dh = 0; dh < 3; ++dh)
#pragma unroll
                for (int dw = 0; dw < 3; ++dw) {
                    int off = (sh + dh - 1) * 512 + (sw + dw - 1);
                    float n1 = b1[off], n2 = b2[off];
                    float t1 = n1 - y2, t2 = n2 - y1;
                    a1[dh * 3 + dw] = fmaf(t1, t1, a1[dh * 3 + dw]);
                    a2[dh * 3 + dw] = fmaf(t2, t2, a2[dh * 3 + dw]);
                }
        }
        float s1 = 0.f, s2 = 0.f;
        float d1[9], d2[9];
#pragma unroll
        for (int k = 0; k < 9; ++k) {
            d1[k] = 1.0f / sqrtf(a1[k] + 0.01f);
            d2[k] = 1.0f / sqrtf(a2[k] + 0.01f);
            s1 += d1[k];
            s2 += d2[k];
        }
        float i1 = 1.0f / s1, i2 = 1.0f / s2;
#pragma unroll
        for (int k = 0; k < 9; ++k) { d[k] = d1[k] * i1; d[9 + k] = d2[k] * i2; }
    } else {
#pragma unroll
        for (int k = 0; k < 18; ++k) d[k] = 1.0f / 9.0f;
    }
    d[18] = 2.0f * sh / 511.0f - 1.0f;
    d[19] = 2.0f * sw / 511.0f - 1.0f;
    // 2x2 maxpool: wave = 4 rows of 16; xor1 pairs sw, xor16 pairs sh.
#pragma unroll
    for (int k = 0; k < 20; ++k) {
        float v = d[k];
        v = fmaxf(v, __shfl_xor(v, 1, 64));
        v = fmaxf(v, __shfl_xor(v, 16, 64));
        d[k] = v;
    }
    if (((tx | ty) & 1) == 0) {
        int pix = (sh >> 1) * 256 + (sw >> 1);
#pragma unroll
        for (int k = 0; k < 20; ++k) feat[k * 65536 + pix] = d[k];
    }
}

// pixel_match at 256 res -> feat ch20..39. Channel-split 4 ways + LDS reduce.
// block (64,4): 8x8 pixel tile x 4 channel groups; grid (32,32).
__global__ __launch_bounds__(256) void pm256_kernel(
    const float* __restrict__ p1, const float* __restrict__ p2,
    float* __restrict__ feat) {
    __shared__ float part[4][64][19];
    int lane = threadIdx.x, grp = threadIdx.y;
    int w = blockIdx.x * 8 + (lane & 7);
    int h = blockIdx.y * 8 + (lane >> 3);
    bool interior = (h >= 1 && h <= 254 && w >= 1 && w <= 254);
    float a1[9], a2[9];
#pragma unroll
    for (int k = 0; k < 9; ++k) { a1[k] = 0.f; a2[k] = 0.f; }
    if (interior) {
        int ctr = h * 256 + w;
        for (int c = grp * 8; c < grp * 8 + 8; ++c) {
            const float* b1 = p1 + c * 65536;
            const float* b2 = p2 + c * 65536;
            float y1 = b1[ctr], y2 = b2[ctr];
#pragma unroll
            for (int dh = 0; dh < 3; ++dh)
#pragma unroll
                for (int dw = 0; dw < 3; ++dw) {
                    int off = (h + dh - 1) * 256 + (w + dw - 1);
                    float n1 = b1[off], n2 = b2[off];
                    float t1 = n1 - y2, t2 = n2 - y1;
                    a1[dh * 3 + dw] = fmaf(t1, t1, a1[dh * 3 + dw]);
                    a2[dh * 3 + dw] = fmaf(t2, t2, a2[dh * 3 + dw]);
                }
        }
    }
#pragma unroll
    for (int k = 0; k < 9; ++k) {
        part[grp][lane][k] = a1[k];
        part[grp][lane][k + 9] = a2[k];
    }
    __syncthreads();
    if (grp == 0) {
        int pix = h * 256 + w;
        if (interior) {
            float d1[9], d2[9];
            float s1 = 0.f, s2 = 0.f;
#pragma unroll
            for (int k = 0; k < 9; ++k) {
                float t1 = part[0][lane][k] + part[1][lane][k] +
                           part[2][lane][k] + part[3][lane][k];
                float t2 = part[0][lane][k + 9] + part[1][lane][k + 9] +
                           part[2][lane][k + 9] + part[3][lane][k + 9];
                d1[k] = 1.0f / sqrtf(t1 + 0.01f);
                d2[k] = 1.0f / sqrtf(t2 + 0.01f);
                s1 += d1[k];
                s2 += d2[k];
            }
            float i1 = 1.0f / s1, i2 = 1.0f / s2;
#pragma unroll
            for (int k = 0; k < 9; ++k) {
                feat[(20 + k) * 65536 + pix] = d1[k] * i1;
                feat[(29 + k) * 65536 + pix] = d2[k] * i2;
            }
        } else {
#pragma unroll
            for (int k = 0; k < 18; ++k)
                feat[(20 + k) * 65536 + pix] = 1.0f / 9.0f;
        }
        feat[38 * 65536 + pix] = 2.0f * h / 255.0f - 1.0f;
        feat[39 * 65536 + pix] = 2.0f * w / 255.0f - 1.0f;
    }
}

// conv5x5 (32->8, pad 2) on (p1-p2) + leaky_relu -> feat ch40..47.
// o-split: grid (16,16,8), one output channel per z.
__global__ __launch_bounds__(256) void dense_kernel(
    const float* __restrict__ p1, const float* __restrict__ p2,
    const float* __restrict__ dw, const float* __restrict__ db,
    float* __restrict__ feat) {
    __shared__ float sw[800];
    int o = blockIdx.z;
    int tx = threadIdx.x, ty = threadIdx.y;
    int tid = ty * 16 + tx;
    for (int i = tid; i < 800; i += 256) sw[i] = dw[o * 800 + i];
    __syncthreads();
    int h = blockIdx.y * 16 + ty, w = blockIdx.x * 16 + tx;
    float acc = db[o];
    for (int ci = 0; ci < 32; ++ci) {
        const float* b1 = p1 + ci * 65536;
        const float* b2 = p2 + ci * 65536;
        const float* wc = &sw[ci * 25];
#pragma unroll
        for (int ky = 0; ky < 5; ++ky) {
            int yy = h + ky - 2;
            if (yy < 0 || yy >= 256) continue;
#pragma unroll
            for (int kx = 0; kx < 5; ++kx) {
                int xx = w + kx - 2;
                if (xx < 0 || xx >= 256) continue;
                float v = b1[yy * 256 + xx] - b2[yy * 256 + xx];
                acc = fmaf(wc[ky * 5 + kx], v, acc);
            }
        }
    }
    float v = (acc >= 0.f) ? acc : 0.01f * acc;
    feat[(40 + o) * 65536 + h * 256 + w] = v;
}

// 1x1 conv 48->64, o-split 4 ways: grid (256,4).
__global__ __launch_bounds__(256) void f1_kernel(
    const float* __restrict__ feat, const float* __restrict__ f1w,
    const float* __restrict__ f1b, float* __restrict__ out) {
    __shared__ float sw[768];
    __shared__ float sb[16];
    int og = blockIdx.y;
    int tid = threadIdx.x;
    for (int i = tid; i < 768; i += 256) sw[i] = f1w[og * 768 + i];
    if (tid < 16) sb[tid] = f1b[og * 16 + tid];
    __syncthreads();
    int pix = blockIdx.x * 256 + tid;
    float f[48];
#pragma unroll
    for (int c = 0; c < 48; ++c) f[c] = feat[c * 65536 + pix];
#pragma unroll
    for (int o = 0; o < 16; ++o) {
        float a = sb[o];
        const float4* wv = (const float4*)&sw[o * 48];
#pragma unroll
        for (int c4 = 0; c4 < 12; ++c4) {
            float4 ww = wv[c4];
            a = fmaf(ww.x, f[c4 * 4], a);
            a = fmaf(ww.y, f[c4 * 4 + 1], a);
            a = fmaf(ww.z, f[c4 * 4 + 2], a);
            a = fmaf(ww.w, f[c4 * 4 + 3], a);
        }
        out[(og * 16 + o) * 65536 + pix] = a;
    }
}

// adaptive_max_pool3: one block per (channel, i, j); overlapping regions.
__global__ __launch_bounds__(256) void pool3_kernel(
    const float* __restrict__ f1out, float* __restrict__ pooled) {
    int b = blockIdx.x;  // 64*9
    int c = b / 9, ij = b % 9, i = ij / 3, j = ij % 3;
    int hs = (i * 256) / 3, he = ((i + 1) * 256 + 2) / 3;
    int ws = (j * 256) / 3, we = ((j + 1) * 256 + 2) / 3;
    const float* src = f1out + c * 65536;
    int nh = he - hs, nw = we - ws, tot = nh * nw;
    float m = -INFINITY;
    for (int t = threadIdx.x; t < tot; t += 256) {
        int r = t / nw, q = t - r * nw;
        m = fmaxf(m, src[(hs + r) * 256 + (ws + q)]);
    }
    for (int off = 32; off > 0; off >>= 1) m = fmaxf(m, __shfl_down(m, off, 64));
    __shared__ float red[4];
    if ((threadIdx.x & 63) == 0) red[threadIdx.x >> 6] = m;
    __syncthreads();
    if (threadIdx.x == 0)
        pooled[b] = fmaxf(fmaxf(red[0], red[1]), fmaxf(red[2], red[3]));
}

// f2 conv (64,3,3)->128, L2-normalize, f3 matmul -> 6, assemble 3x3 output.
__global__ __launch_bounds__(128) void final_kernel(
    const float* __restrict__ pooled, const float* __restrict__ f2w,
    const float* __restrict__ f2b, const float* __restrict__ f3w,
    const float* __restrict__ f3b, float* __restrict__ out) {
    __shared__ float xn[128];
    __shared__ float red[2];
    __shared__ float ov[6];
    int t = threadIdx.x;
    float a = f2b[t];
    for (int c = 0; c < 64; ++c)
#pragma unroll
        for (int k = 0; k < 9; ++k)
            a = fmaf(f2w[t * 576 + c * 9 + k], pooled[c * 9 + k], a);
    float sq = a * a;
    for (int off = 32; off > 0; off >>= 1) sq += __shfl_down(sq, off, 64);
    if ((t & 63) == 0) red[t >> 6] = sq;
    __syncthreads();
    float tmp = red[0] + red[1] + 0.001f;
    float scale = 1.0f / sqrtf(tmp);
    xn[t] = a * scale;
    __syncthreads();
    if (t < 6) {
        float o = f3b[t];
        for (int k = 0; k < 128; ++k) o = fmaf(f3w[t * 128 + k], xn[k], o);
        ov[t] = o;
    }
    __syncthreads();
    if (t < 9) {
        int r = t / 3, cc = t % 3;
        float v = 0.f;
        if (r < 2) {
            float x = ov[r * 3 + cc];
            float cl = fminf(fmaxf(x, -0.11f), 0.11f);
            v = cl + 0.01f * x;
        }
        if (r == cc) v += 1.0f;
        out[t] = v;
    }
}

extern "C" void kernel_launch(void* const* d_in, const int* in_sizes, int n_in,
                              void* d_out, int out_size, void* d_ws,
                              size_t ws_size, hipStream_t stream) {
    const float* x1 = (const float*)d_in[0];
    const float* x2 = (const float*)d_in[1];
    const float* enc_w = (const float*)d_in[2];
    const float* enc_b = (const float*)d_in[3];
    const float* embed_w = (const float*)d_in[4];
    const float* embed_b = (const float*)d_in[5];
    const float* dense_w = (const float*)d_in[6];
    const float* dense_b = (const float*)d_in[7];
    const float* f1_w = (const float*)d_in[8];
    const float* f1_b = (const float*)d_in[9];
    const float* f2_w = (const float*)d_in[10];
    const float* f2_b = (const float*)d_in[11];
    const float* f3_w = (const float*)d_in[12];
    const float* f3_b = (const float*)d_in[13];

    float* ws = (float*)d_ws;
    float* weff_t = ws;                 // 864
    float* beff = ws + 864;             // 32
    float* c1 = ws + 1024;              // 32*512*512 = 8388608
    float* c2 = c1 + 8388608;
    float* p1 = c2 + 8388608;           // 32*256*256 = 2097152
    float* p2 = p1 + 2097152;
    float* feat = p2 + 2097152;         // 48*256*256 = 3145728
    float* pooled = feat + 3145728;     // 576
    float* f1o = c1;                    // alias: c1 dead after pm512

    fuse_weights_kernel<<<1, 256, 0, stream>>>(enc_w, enc_b, embed_w, embed_b,
                                               weff_t, beff);
    coding_kernel<<<dim3(32, 32, 2), dim3(16, 16), 0, stream>>>(
        x1, x2, weff_t, beff, c1, c2);
    maxpool_kernel<<<(2 * 32 * 65536 + 255) / 256, 256, 0, stream>>>(c1, c2, p1,
                                                                     p2);
    pm512_pool_kernel<<<dim3(32, 32), dim3(16, 16), 0, stream>>>(c1, c2, feat);
    pm256_kernel<<<dim3(32, 32), dim3(64, 4), 0, stream>>>(p1, p2, feat);
    dense_kernel<<<dim3(16, 16, 8), dim3(16, 16), 0, stream>>>(
        p1, p2, dense_w, dense_b, feat);
    f1_kernel<<<dim3(256, 4), 256, 0, stream>>>(feat, f1_w, f1_b, f1o);
    pool3_kernel<<<576, 256, 0, stream>>>(f1o, pooled);
    final_kernel<<<1, 128, 0, stream>>>(pooled, f2_w, f2_b, f3_w, f3_b,
                                        (float*)d_out);
}

// Round 3
// 277.631 us; speedup vs baseline: 1.6239x; 1.5632x over previous
//
#include <hip/hip_runtime.h>
#include <math.h>

// ---------------------------------------------------------------------------
// MyNet: two 1024x1024x3 images -> 3x3 matrix.
// R3: dense conv redone as ci-split (z=8 x 4ci) + LDS diff tile + 2x2 px/thread
//     partials in scratch, reduce(+bias+leaky) pass. maxpool fused into coding
//     via shfl 2x2 reduce. f1 o-split 4->2.
// ---------------------------------------------------------------------------

__global__ void fuse_weights_kernel(const float* __restrict__ enc_w,
                                    const float* __restrict__ enc_b,
                                    const float* __restrict__ embed_w,
                                    const float* __restrict__ embed_b,
                                    float* __restrict__ weff_t,
                                    float* __restrict__ beff) {
    int t = threadIdx.x;
    for (int idx = t; idx < 27 * 32; idx += blockDim.x) {
        int r = idx >> 5, o = idx & 31;
        float s = 0.f;
        for (int k = 0; k < 24; ++k) s += embed_w[o * 24 + k] * enc_w[k * 27 + r];
        weff_t[idx] = s;
    }
    if (t < 32) {
        float s = embed_b[t];
        for (int k = 0; k < 24; ++k) s += embed_w[t * 24 + k] * enc_b[k];
        beff[t] = s;
    }
}

// Fused enc+embed 3x3 conv (3->32) + maxpool2 -> c (512^2), and a second
// fused 2x2 shfl maxpool -> p (256^2). One thread per c-pixel.
__global__ __launch_bounds__(256) void coding_kernel(
    const float* __restrict__ x1, const float* __restrict__ x2,
    const float* __restrict__ weff_t, const float* __restrict__ beff,
    float* __restrict__ c1, float* __restrict__ c2,
    float* __restrict__ p1, float* __restrict__ p2) {
    __shared__ float swT[864];  // [27][32]
    __shared__ float sb[32];
    int tx = threadIdx.x, ty = threadIdx.y;
    int tid = ty * 16 + tx;
    for (int i = tid; i < 864; i += 256) swT[i] = weff_t[i];
    if (tid < 32) sb[tid] = beff[tid];
    __syncthreads();
    const float* x = blockIdx.z ? x2 : x1;
    float* c = blockIdx.z ? c2 : c1;
    float* p = blockIdx.z ? p2 : p1;
    int h = blockIdx.y * 16 + ty, w = blockIdx.x * 16 + tx;
    int Y = 2 * h, X = 2 * w;
    float in[3][4][4];
    bool interior_blk = (blockIdx.x > 0 && blockIdx.x < 31 &&
                         blockIdx.y > 0 && blockIdx.y < 31);
    if (interior_blk) {
#pragma unroll
        for (int ci = 0; ci < 3; ++ci)
#pragma unroll
            for (int yy = 0; yy < 4; ++yy) {
                const float* row = x + ci * 1048576 + (Y - 1 + yy) * 1024 + X - 1;
#pragma unroll
                for (int xx = 0; xx < 4; ++xx) in[ci][yy][xx] = row[xx];
            }
    } else {
#pragma unroll
        for (int ci = 0; ci < 3; ++ci)
#pragma unroll
            for (int yy = 0; yy < 4; ++yy)
#pragma unroll
                for (int xx = 0; xx < 4; ++xx) {
                    int gy = Y - 1 + yy, gx = X - 1 + xx;
                    in[ci][yy][xx] =
                        (gy >= 0 && gy < 1024 && gx >= 0 && gx < 1024)
                            ? x[ci * 1048576 + gy * 1024 + gx]
                            : 0.f;
                }
    }
    int pix = h * 512 + w;
    int ppix = (h >> 1) * 256 + (w >> 1);
    bool pwrite = (((tx | ty) & 1) == 0);
#pragma unroll
    for (int og = 0; og < 2; ++og) {
        float acc[4][16];
#pragma unroll
        for (int pq = 0; pq < 4; ++pq)
#pragma unroll
            for (int oo = 0; oo < 16; ++oo) acc[pq][oo] = sb[og * 16 + oo];
#pragma unroll
        for (int ci = 0; ci < 3; ++ci)
#pragma unroll
            for (int ky = 0; ky < 3; ++ky)
#pragma unroll
                for (int kx = 0; kx < 3; ++kx) {
                    const float4* wp =
                        (const float4*)&swT[(ci * 9 + ky * 3 + kx) * 32 + og * 16];
                    float4 w0 = wp[0], w1 = wp[1], w2 = wp[2], w3 = wp[3];
                    float wv[16] = {w0.x, w0.y, w0.z, w0.w, w1.x, w1.y, w1.z, w1.w,
                                    w2.x, w2.y, w2.z, w2.w, w3.x, w3.y, w3.z, w3.w};
#pragma unroll
                    for (int pq = 0; pq < 4; ++pq) {
                        float xv = in[ci][(pq >> 1) + ky][(pq & 1) + kx];
#pragma unroll
                        for (int oo = 0; oo < 16; ++oo)
                            acc[pq][oo] = fmaf(wv[oo], xv, acc[pq][oo]);
                    }
                }
#pragma unroll
        for (int oo = 0; oo < 16; ++oo) {
            float m = fmaxf(fmaxf(acc[0][oo], acc[1][oo]),
                            fmaxf(acc[2][oo], acc[3][oo]));
            c[(og * 16 + oo) * 262144 + pix] = m;
            // fused maxpool2 c->p: wave = 4 rows of 16; xor1 = w-pair, xor16 = h-pair
            float v = fmaxf(m, __shfl_xor(m, 1, 64));
            v = fmaxf(v, __shfl_xor(v, 16, 64));
            if (pwrite) p[(og * 16 + oo) * 65536 + ppix] = v;
        }
    }
}

// pixel_match at 512 res + fused maxpool2 via in-wave 2x2 shfl reduce.
__global__ __launch_bounds__(256) void pm512_pool_kernel(
    const float* __restrict__ c1, const float* __restrict__ c2,
    float* __restrict__ feat) {
    int tx = threadIdx.x, ty = threadIdx.y;
    int sw = blockIdx.x * 16 + tx;
    int sh = blockIdx.y * 16 + ty;
    float d[20];
    bool interior = (sh >= 1 && sh <= 510 && sw >= 1 && sw <= 510);
    if (interior) {
        float a1[9], a2[9];
#pragma unroll
        for (int k = 0; k < 9; ++k) { a1[k] = 0.f; a2[k] = 0.f; }
        int ctr = sh * 512 + sw;
        for (int c = 0; c < 32; ++c) {
            const float* b1 = c1 + c * 262144;
            const float* b2 = c2 + c * 262144;
            float y1 = b1[ctr], y2 = b2[ctr];
#pragma unroll
            for (int dh = 0; dh < 3; ++dh)
#pragma unroll
                for (int dw = 0; dw < 3; ++dw) {
                    int off = (sh + dh - 1) * 512 + (sw + dw - 1);
                    float n1 = b1[off], n2 = b2[off];
                    float t1 = n1 - y2, t2 = n2 - y1;
                    a1[dh * 3 + dw] = fmaf(t1, t1, a1[dh * 3 + dw]);
                    a2[dh * 3 + dw] = fmaf(t2, t2, a2[dh * 3 + dw]);
                }
        }
        float s1 = 0.f, s2 = 0.f;
        float d1[9], d2[9];
#pragma unroll
        for (int k = 0; k < 9; ++k) {
            d1[k] = 1.0f / sqrtf(a1[k] + 0.01f);
            d2[k] = 1.0f / sqrtf(a2[k] + 0.01f);
            s1 += d1[k];
            s2 += d2[k];
        }
        float i1 = 1.0f / s1, i2 = 1.0f / s2;
#pragma unroll
        for (int k = 0; k < 9; ++k) { d[k] = d1[k] * i1; d[9 + k] = d2[k] * i2; }
    } else {
#pragma unroll
        for (int k = 0; k < 18; ++k) d[k] = 1.0f / 9.0f;
    }
    d[18] = 2.0f * sh / 511.0f - 1.0f;
    d[19] = 2.0f * sw / 511.0f - 1.0f;
#pragma unroll
    for (int k = 0; k < 20; ++k) {
        float v = d[k];
        v = fmaxf(v, __shfl_xor(v, 1, 64));
        v = fmaxf(v, __shfl_xor(v, 16, 64));
        d[k] = v;
    }
    if (((tx | ty) & 1) == 0) {
        int pix = (sh >> 1) * 256 + (sw >> 1);
#pragma unroll
        for (int k = 0; k < 20; ++k) feat[k * 65536 + pix] = d[k];
    }
}

// pixel_match at 256 res -> feat ch20..39. Channel-split 4 ways + LDS reduce.
__global__ __launch_bounds__(256) void pm256_kernel(
    const float* __restrict__ p1, const float* __restrict__ p2,
    float* __restrict__ feat) {
    __shared__ float part[4][64][19];
    int lane = threadIdx.x, grp = threadIdx.y;
    int w = blockIdx.x * 8 + (lane & 7);
    int h = blockIdx.y * 8 + (lane >> 3);
    bool interior = (h >= 1 && h <= 254 && w >= 1 && w <= 254);
    float a1[9], a2[9];
#pragma unroll
    for (int k = 0; k < 9; ++k) { a1[k] = 0.f; a2[k] = 0.f; }
    if (interior) {
        int ctr = h * 256 + w;
        for (int c = grp * 8; c < grp * 8 + 8; ++c) {
            const float* b1 = p1 + c * 65536;
            const float* b2 = p2 + c * 65536;
            float y1 = b1[ctr], y2 = b2[ctr];
#pragma unroll
            for (int dh = 0; dh < 3; ++dh)
#pragma unroll
                for (int dw = 0; dw < 3; ++dw) {
                    int off = (h + dh - 1) * 256 + (w + dw - 1);
                    float n1 = b1[off], n2 = b2[off];
                    float t1 = n1 - y2, t2 = n2 - y1;
                    a1[dh * 3 + dw] = fmaf(t1, t1, a1[dh * 3 + dw]);
                    a2[dh * 3 + dw] = fmaf(t2, t2, a2[dh * 3 + dw]);
                }
        }
    }
#pragma unroll
    for (int k = 0; k < 9; ++k) {
        part[grp][lane][k] = a1[k];
        part[grp][lane][k + 9] = a2[k];
    }
    __syncthreads();
    if (grp == 0) {
        int pix = h * 256 + w;
        if (interior) {
            float d1[9], d2[9];
            float s1 = 0.f, s2 = 0.f;
#pragma unroll
            for (int k = 0; k < 9; ++k) {
                float t1 = part[0][lane][k] + part[1][lane][k] +
                           part[2][lane][k] + part[3][lane][k];
                float t2 = part[0][lane][k + 9] + part[1][lane][k + 9] +
                           part[2][lane][k + 9] + part[3][lane][k + 9];
                d1[k] = 1.0f / sqrtf(t1 + 0.01f);
                d2[k] = 1.0f / sqrtf(t2 + 0.01f);
                s1 += d1[k];
                s2 += d2[k];
            }
            float i1 = 1.0f / s1, i2 = 1.0f / s2;
#pragma unroll
            for (int k = 0; k < 9; ++k) {
                feat[(20 + k) * 65536 + pix] = d1[k] * i1;
                feat[(29 + k) * 65536 + pix] = d2[k] * i2;
            }
        } else {
#pragma unroll
            for (int k = 0; k < 18; ++k)
                feat[(20 + k) * 65536 + pix] = 1.0f / 9.0f;
        }
        feat[38 * 65536 + pix] = 2.0f * h / 255.0f - 1.0f;
        feat[39 * 65536 + pix] = 2.0f * w / 255.0f - 1.0f;
    }
}

// Dense conv5x5 partial sums: grid (8,8,8); z = ci group (4 channels).
// Block computes 32x32 output tile (2x2 px/thread), all 8 output channels,
// from an LDS-staged 36x36 diff tile per ci. No bias; partial -> scratch.
__global__ __launch_bounds__(256) void dense_part_kernel(
    const float* __restrict__ p1, const float* __restrict__ p2,
    const float* __restrict__ dw, float* __restrict__ part) {
    __shared__ float sdiff[4 * 1296];   // [4][36][36]
    __shared__ float sw[4 * 8 * 28];    // [ci][o][28], 16B-aligned rows
    int tx = threadIdx.x, ty = threadIdx.y;
    int tid = ty * 16 + tx;
    int bz = blockIdx.z;
    int h0 = blockIdx.y * 32, w0 = blockIdx.x * 32;
    // stage diff tiles
    for (int idx = tid; idx < 4 * 1296; idx += 256) {
        int ci = idx / 1296, r = idx % 1296;
        int yy = r / 36, xx = r % 36;
        int gy = h0 + yy - 2, gx = w0 + xx - 2;
        float v = 0.f;
        if (gy >= 0 && gy < 256 && gx >= 0 && gx < 256) {
            int g = (bz * 4 + ci) * 65536 + gy * 256 + gx;
            v = p1[g] - p2[g];
        }
        sdiff[idx] = v;
    }
    // stage weights [ci][o][k], pad k to 28
    for (int idx = tid; idx < 4 * 8 * 28; idx += 256) {
        int ci = idx / 224, r = idx % 224;
        int o = r / 28, k = r % 28;
        sw[idx] = (k < 25) ? dw[o * 800 + (bz * 4 + ci) * 25 + k] : 0.f;
    }
    __syncthreads();
    float acc[4][8];
#pragma unroll
    for (int pq = 0; pq < 4; ++pq)
#pragma unroll
        for (int o = 0; o < 8; ++o) acc[pq][o] = 0.f;
    for (int ci = 0; ci < 4; ++ci) {
        // 6x6 patch into registers (float2 reads)
        float patch[6][6];
#pragma unroll
        for (int yy = 0; yy < 6; ++yy) {
            const float* rowp = &sdiff[ci * 1296 + (2 * ty + yy) * 36 + 2 * tx];
#pragma unroll
            for (int cpair = 0; cpair < 3; ++cpair) {
                float2 lp = *(const float2*)&rowp[2 * cpair];
                patch[yy][2 * cpair] = lp.x;
                patch[yy][2 * cpair + 1] = lp.y;
            }
        }
#pragma unroll
        for (int o = 0; o < 8; ++o) {
            float wreg[28];
            const float4* wp = (const float4*)&sw[(ci * 8 + o) * 28];
#pragma unroll
            for (int q = 0; q < 7; ++q) {
                float4 wv = wp[q];
                wreg[4 * q] = wv.x;
                wreg[4 * q + 1] = wv.y;
                wreg[4 * q + 2] = wv.z;
                wreg[4 * q + 3] = wv.w;
            }
#pragma unroll
            for (int ky = 0; ky < 5; ++ky)
#pragma unroll
                for (int kx = 0; kx < 5; ++kx) {
                    float wv = wreg[ky * 5 + kx];
#pragma unroll
                    for (int pq = 0; pq < 4; ++pq)
                        acc[pq][o] = fmaf(
                            wv, patch[ky + (pq >> 1)][kx + (pq & 1)], acc[pq][o]);
                }
        }
    }
    // write partials: part[bz][o][pix]
#pragma unroll
    for (int pq = 0; pq < 4; ++pq) {
        int h = h0 + 2 * ty + (pq >> 1), w = w0 + 2 * tx + (pq & 1);
        int pix = h * 256 + w;
#pragma unroll
        for (int o = 0; o < 8; ++o)
            part[bz * 524288 + o * 65536 + pix] = acc[pq][o];
    }
}

// Reduce 8 partials + bias + leaky_relu -> feat ch40..47.
__global__ __launch_bounds__(256) void dense_reduce_kernel(
    const float* __restrict__ part, const float* __restrict__ db,
    float* __restrict__ feat) {
    int idx = blockIdx.x * 256 + threadIdx.x;  // o*65536+pix, 524288 total
    int o = idx >> 16;
    float s = db[o];
#pragma unroll
    for (int z = 0; z < 8; ++z) s += part[z * 524288 + idx];
    float v = (s >= 0.f) ? s : 0.01f * s;
    feat[40 * 65536 + idx] = v;
}

// 1x1 conv 48->64, o-split 2 ways: grid (256,2), 32 outputs each.
__global__ __launch_bounds__(256) void f1_kernel(
    const float* __restrict__ feat, const float* __restrict__ f1w,
    const float* __restrict__ f1b, float* __restrict__ out) {
    __shared__ float sw[1536];
    __shared__ float sb[32];
    int og = blockIdx.y;
    int tid = threadIdx.x;
    for (int i = tid; i < 1536; i += 256) sw[i] = f1w[og * 1536 + i];
    if (tid < 32) sb[tid] = f1b[og * 32 + tid];
    __syncthreads();
    int pix = blockIdx.x * 256 + tid;
    float f[48];
#pragma unroll
    for (int c = 0; c < 48; ++c) f[c] = feat[c * 65536 + pix];
#pragma unroll
    for (int o = 0; o < 32; ++o) {
        float a = sb[o];
        const float4* wv = (const float4*)&sw[o * 48];
#pragma unroll
        for (int c4 = 0; c4 < 12; ++c4) {
            float4 ww = wv[c4];
            a = fmaf(ww.x, f[c4 * 4], a);
            a = fmaf(ww.y, f[c4 * 4 + 1], a);
            a = fmaf(ww.z, f[c4 * 4 + 2], a);
            a = fmaf(ww.w, f[c4 * 4 + 3], a);
        }
        out[(og * 32 + o) * 65536 + pix] = a;
    }
}

// adaptive_max_pool3: one block per (channel, i, j); overlapping regions.
__global__ __launch_bounds__(256) void pool3_kernel(
    const float* __restrict__ f1out, float* __restrict__ pooled) {
    int b = blockIdx.x;  // 64*9
    int c = b / 9, ij = b % 9, i = ij / 3, j = ij % 3;
    int hs = (i * 256) / 3, he = ((i + 1) * 256 + 2) / 3;
    int ws = (j * 256) / 3, we = ((j + 1) * 256 + 2) / 3;
    const float* src = f1out + c * 65536;
    int nh = he - hs, nw = we - ws, tot = nh * nw;
    float m = -INFINITY;
    for (int t = threadIdx.x; t < tot; t += 256) {
        int r = t / nw, q = t - r * nw;
        m = fmaxf(m, src[(hs + r) * 256 + (ws + q)]);
    }
    for (int off = 32; off > 0; off >>= 1) m = fmaxf(m, __shfl_down(m, off, 64));
    __shared__ float red[4];
    if ((threadIdx.x & 63) == 0) red[threadIdx.x >> 6] = m;
    __syncthreads();
    if (threadIdx.x == 0)
        pooled[b] = fmaxf(fmaxf(red[0], red[1]), fmaxf(red[2], red[3]));
}

// f2 conv (64,3,3)->128, L2-normalize, f3 matmul -> 6, assemble 3x3 output.
__global__ __launch_bounds__(128) void final_kernel(
    const float* __restrict__ pooled, const float* __restrict__ f2w,
    const float* __restrict__ f2b, const float* __restrict__ f3w,
    const float* __restrict__ f3b, float* __restrict__ out) {
    __shared__ float xn[128];
    __shared__ float red[2];
    __shared__ float ov[6];
    int t = threadIdx.x;
    float a = f2b[t];
    for (int c = 0; c < 64; ++c)
#pragma unroll
        for (int k = 0; k < 9; ++k)
            a = fmaf(f2w[t * 576 + c * 9 + k], pooled[c * 9 + k], a);
    float sq = a * a;
    for (int off = 32; off > 0; off >>= 1) sq += __shfl_down(sq, off, 64);
    if ((t & 63) == 0) red[t >> 6] = sq;
    __syncthreads();
    float tmp = red[0] + red[1] + 0.001f;
    float scale = 1.0f / sqrtf(tmp);
    xn[t] = a * scale;
    __syncthreads();
    if (t < 6) {
        float o = f3b[t];
        for (int k = 0; k < 128; ++k) o = fmaf(f3w[t * 128 + k], xn[k], o);
        ov[t] = o;
    }
    __syncthreads();
    if (t < 9) {
        int r = t / 3, cc = t % 3;
        float v = 0.f;
        if (r < 2) {
            float x = ov[r * 3 + cc];
            float cl = fminf(fmaxf(x, -0.11f), 0.11f);
            v = cl + 0.01f * x;
        }
        if (r == cc) v += 1.0f;
        out[t] = v;
    }
}

extern "C" void kernel_launch(void* const* d_in, const int* in_sizes, int n_in,
                              void* d_out, int out_size, void* d_ws,
                              size_t ws_size, hipStream_t stream) {
    const float* x1 = (const float*)d_in[0];
    const float* x2 = (const float*)d_in[1];
    const float* enc_w = (const float*)d_in[2];
    const float* enc_b = (const float*)d_in[3];
    const float* embed_w = (const float*)d_in[4];
    const float* embed_b = (const float*)d_in[5];
    const float* dense_w = (const float*)d_in[6];
    const float* dense_b = (const float*)d_in[7];
    const float* f1_w = (const float*)d_in[8];
    const float* f1_b = (const float*)d_in[9];
    const float* f2_w = (const float*)d_in[10];
    const float* f2_b = (const float*)d_in[11];
    const float* f3_w = (const float*)d_in[12];
    const float* f3_b = (const float*)d_in[13];

    float* ws = (float*)d_ws;
    float* weff_t = ws;                 // 864
    float* beff = ws + 864;             // 32
    float* c1 = ws + 1024;              // 32*512*512 = 8388608
    float* c2 = c1 + 8388608;
    float* p1 = c2 + 8388608;           // 32*256*256 = 2097152
    float* p2 = p1 + 2097152;
    float* feat = p2 + 2097152;         // 48*256*256 = 3145728
    float* pooled = feat + 3145728;     // 576
    float* f1o = c1;                    // alias: c1 dead after pm512
    float* part = c2;                   // alias: c2 dead after pm512 (4.2M)

    fuse_weights_kernel<<<1, 256, 0, stream>>>(enc_w, enc_b, embed_w, embed_b,
                                               weff_t, beff);
    coding_kernel<<<dim3(32, 32, 2), dim3(16, 16), 0, stream>>>(
        x1, x2, weff_t, beff, c1, c2, p1, p2);
    pm512_pool_kernel<<<dim3(32, 32), dim3(16, 16), 0, stream>>>(c1, c2, feat);
    pm256_kernel<<<dim3(32, 32), dim3(64, 4), 0, stream>>>(p1, p2, feat);
    dense_part_kernel<<<dim3(8, 8, 8), dim3(16, 16), 0, stream>>>(
        p1, p2, dense_w, part);
    dense_reduce_kernel<<<2048, 256, 0, stream>>>(part, dense_b, feat);
    f1_kernel<<<dim3(256, 2), 256, 0, stream>>>(feat, f1_w, f1_b, f1o);
    pool3_kernel<<<576, 256, 0, stream>>>(f1o, pooled);
    final_kernel<<<1, 128, 0, stream>>>(pooled, f2_w, f2_b, f3_w, f3_b,
                                        (float*)d_out);
}